// Round 3
// baseline (696.483 us; speedup 1.0000x reference)
//
#include <hip/hip_runtime.h>
#include <hip/hip_bf16.h>
#include <stdint.h>

#define LSEQ 200
#define DDIM 128
#define PAD 138  // bf16 row stride: 69 banks == 5 mod 32 -> 2-way max on b128 reads

typedef __attribute__((ext_vector_type(8))) __bf16 bf16x8;
typedef __attribute__((ext_vector_type(4))) float f32x4;

__device__ __forceinline__ float fast_exp(float x) {
  return __builtin_amdgcn_exp2f(x * 1.4426950408889634f);
}
__device__ __forceinline__ float fast_sigmoid(float x) {
  return __builtin_amdgcn_rcpf(1.0f + fast_exp(-x));
}
__device__ __forceinline__ float fast_tanh(float x) {
  float ax = __builtin_fabsf(x);
  float t = __builtin_amdgcn_exp2f(ax * -2.885390081777927f);  // exp(-2|x|)
  float r = (1.0f - t) * __builtin_amdgcn_rcpf(1.0f + t);
  return x < 0.0f ? -r : r;
}
__device__ __forceinline__ f32x4 mfma16(bf16x8 a, bf16x8 b, f32x4 c) {
  return __builtin_amdgcn_mfma_f32_16x16x32_bf16(a, b, c, 0, 0, 0);
}
__device__ __forceinline__ bf16x8 pack8(float4 a, float4 b) {
  bf16x8 r;
  r[0] = (__bf16)a.x; r[1] = (__bf16)a.y; r[2] = (__bf16)a.z; r[3] = (__bf16)a.w;
  r[4] = (__bf16)b.x; r[5] = (__bf16)b.y; r[6] = (__bf16)b.z; r[7] = (__bf16)b.w;
  return r;
}

// Kernel 1: target-aware scores + masked softmax -> attnT[b16][t][row] (0 where masked)
__global__ __launch_bounds__(512) void k_scores(
    const float* __restrict__ h_states, const float* __restrict__ target,
    const int* __restrict__ mask, float* __restrict__ attnT, int B) {
  __shared__ float s_sc[4][16][LSEQ];
  __shared__ float s_tgt[16][DDIM];
  const int b16 = blockIdx.x;
  const int bb = b16 * 16;
  const int tid = threadIdx.x;
  for (int i = tid; i < 16 * DDIM; i += 512)
    s_tgt[i >> 7][i & 127] = target[(size_t)(bb + (i >> 7)) * DDIM + (i & 127)];
  __syncthreads();

  {
    const int lane = tid & 63;
    const int kt = (tid >> 6) & 3;
    const int tp = tid >> 8;
    const int row = lane & 15;
    const int hi = lane >> 4;
    const int kbase = kt * 32 + hi * 8;
    const float* src = h_states + ((size_t)(bb + row) * LSEQ) * DDIM + kbase;
    const float* tg = &s_tgt[row][kbase];
#pragma unroll 2
    for (int t = tp; t < LSEQ; t += 2) {
      float4 a = *(const float4*)(src + (size_t)t * DDIM);
      float4 b = *(const float4*)(src + (size_t)t * DDIM + 4);
      float dv = (a.x * tg[0] + a.y * tg[1] + a.z * tg[2] + a.w * tg[3]) +
                 (b.x * tg[4] + b.y * tg[5] + b.z * tg[6] + b.w * tg[7]);
      dv += __shfl_xor(dv, 16);
      dv += __shfl_xor(dv, 32);
      if (hi == 0) s_sc[kt][row][t] = dv;
    }
  }
  __syncthreads();

  if (tid < 256) {
    const int r2 = tid >> 4;
    const int j = tid & 15;
    const int* mrow = mask + (size_t)(bb + r2) * LSEQ;
    float mx = -3.0e38f;
    for (int t = j; t < LSEQ; t += 16) {
      float s = (s_sc[0][r2][t] + s_sc[1][r2][t]) + (s_sc[2][r2][t] + s_sc[3][r2][t]);
      s *= 0.088388347648318447f;  // 1/sqrt(128)
      s = (mrow[t] != 0) ? s : -3.0e38f;
      s_sc[0][r2][t] = s;
      mx = fmaxf(mx, s);
    }
    mx = fmaxf(mx, __shfl_xor(mx, 1));
    mx = fmaxf(mx, __shfl_xor(mx, 2));
    mx = fmaxf(mx, __shfl_xor(mx, 4));
    mx = fmaxf(mx, __shfl_xor(mx, 8));
    float se = 0.0f;
    for (int t = j; t < LSEQ; t += 16) {
      float e = fast_exp(s_sc[0][r2][t] - mx);
      s_sc[1][r2][t] = e;
      se += e;
    }
    se += __shfl_xor(se, 1);
    se += __shfl_xor(se, 2);
    se += __shfl_xor(se, 4);
    se += __shfl_xor(se, 8);
    float rs = __builtin_amdgcn_rcpf(se);
    for (int t = j; t < LSEQ; t += 16)
      attnT[((size_t)b16 * LSEQ + t) * 16 + r2] =
          (mrow[t] != 0) ? s_sc[1][r2][t] * rs : 0.0f;
  }
}

// One recurrence step. XC holds fp32 x_{t+1} (feeds next step's precomputed
// x-part accs AX*N); XN receives the 2-step-ahead prefetch of x_{t+2}.
#define STEP(t, XC, XN, AXRC, AXUC, AXHC, AXRN, AXUN, AXHN)                  \
  do {                                                                       \
    if ((t) + 2 < LSEQ) {                                                    \
      _Pragma("unroll") for (int kt = 0; kt < 4; ++kt) {                     \
        XN[2 * kt] = *(const float4*)(srcx + (size_t)((t) + 2) * DDIM + kt * 32); \
        XN[2 * kt + 1] =                                                     \
            *(const float4*)(srcx + (size_t)((t) + 2) * DDIM + kt * 32 + 4); \
      }                                                                      \
    }                                                                        \
    f32x4 att4 = *(const f32x4*)&s_att[(t)][g * 4];                          \
    bf16x8 hf[4];                                                            \
    _Pragma("unroll") for (int kt = 0; kt < 4; ++kt)                         \
        hf[kt] = *(const bf16x8*)&s_hb[rA][kt * 32 + g * 8];                 \
    f32x4 accr = AXRC, accu = AXUC;                                          \
    bf16x8 af[4];                                                            \
    if ((t) + 1 < LSEQ) { /* next step's x-part: independent MFMAs */        \
      _Pragma("unroll") for (int kt = 0; kt < 4; ++kt)                       \
          af[kt] = pack8(XC[2 * kt], XC[2 * kt + 1]);                        \
      AXRN = (f32x4){biasr, biasr, biasr, biasr};                            \
      AXUN = (f32x4){biasu, biasu, biasu, biasu};                            \
      _Pragma("unroll") for (int kt = 0; kt < 4; ++kt) {                     \
        AXRN = mfma16(af[kt], wr[kt], AXRN);                                 \
        AXUN = mfma16(af[kt], wu[kt], AXUN);                                 \
      }                                                                      \
    }                                                                        \
    _Pragma("unroll") for (int kt = 0; kt < 4; ++kt) {                       \
      accr = mfma16(hf[kt], wr[4 + kt], accr);                               \
      accu = mfma16(hf[kt], wu[4 + kt], accu);                               \
    }                                                                        \
    float rr[4], uu[4];                                                      \
    _Pragma("unroll") for (int j = 0; j < 4; ++j) {                          \
      rr[j] = fast_sigmoid(accr[j]);                                         \
      uu[j] = fast_sigmoid(accu[j]);                                         \
      s_rh[g * 4 + j][col] = (__bf16)(rr[j] * hD[j]);                        \
    }                                                                        \
    __builtin_amdgcn_sched_barrier(0);                                       \
    asm volatile("s_waitcnt lgkmcnt(0)" ::: "memory");                       \
    __builtin_amdgcn_s_barrier();                                            \
    __builtin_amdgcn_sched_barrier(0);                                       \
    bf16x8 rf[4];                                                            \
    _Pragma("unroll") for (int kt = 0; kt < 4; ++kt)                         \
        rf[kt] = *(const bf16x8*)&s_rh[rA][kt * 32 + g * 8];                 \
    f32x4 acch = AXHC;                                                       \
    if ((t) + 1 < LSEQ) {                                                    \
      AXHN = (f32x4){biash, biash, biash, biash};                            \
      _Pragma("unroll") for (int kt = 0; kt < 4; ++kt)                       \
          AXHN = mfma16(af[kt], wh[kt], AXHN);                               \
    }                                                                        \
    _Pragma("unroll") for (int kt = 0; kt < 4; ++kt)                         \
        acch = mfma16(rf[kt], wh[4 + kt], acch);                             \
    _Pragma("unroll") for (int j = 0; j < 4; ++j) {                          \
      float ht = fast_tanh(acch[j]);                                         \
      float up = att4[j] * uu[j];                                            \
      hD[j] += up * (ht - hD[j]);                                            \
      s_hb[g * 4 + j][col] = (__bf16)hD[j];                                  \
    }                                                                        \
    __builtin_amdgcn_sched_barrier(0);                                       \
    asm volatile("s_waitcnt lgkmcnt(0)" ::: "memory");                       \
    __builtin_amdgcn_s_barrier();                                            \
    __builtin_amdgcn_sched_barrier(0);                                       \
  } while (0)

__global__ __launch_bounds__(512, 2) void k_recur(
    const float* __restrict__ h_states, const float* __restrict__ attnT,
    const float* __restrict__ Wr, const float* __restrict__ br,
    const float* __restrict__ Wu, const float* __restrict__ bu,
    const float* __restrict__ Wh, const float* __restrict__ bh,
    float* __restrict__ out, int B) {
  __shared__ __bf16 s_rh[16][PAD];
  __shared__ __bf16 s_hb[16][PAD];
  __shared__ float s_att[LSEQ][16];
  const int tid = threadIdx.x;
  const int lane = tid & 63;
  const int wv = tid >> 6;
  const int b16 = blockIdx.x;
  const int bb = b16 * 16;
  const int g = lane >> 4;
  const int rA = lane & 15;
  const int col = wv * 16 + rA;

  // Weights -> bf16 B-frags in VGPRs (held for all 200 steps)
  bf16x8 wr[8], wu[8], wh[8];
#pragma unroll
  for (int kt = 0; kt < 8; ++kt) {
    bf16x8 tr, tu, th;
    int krow = kt * 32 + g * 8;
#pragma unroll
    for (int j = 0; j < 8; ++j) {
      tr[j] = (__bf16)Wr[(size_t)(krow + j) * DDIM + col];
      tu[j] = (__bf16)Wu[(size_t)(krow + j) * DDIM + col];
      th[j] = (__bf16)Wh[(size_t)(krow + j) * DDIM + col];
    }
    wr[kt] = tr; wu[kt] = tu; wh[kt] = th;
  }
  const float biasr = br[col], biasu = bu[col], biash = bh[col];

  for (int i = tid; i < LSEQ * 16; i += 512)
    s_att[i >> 4][i & 15] = attnT[(size_t)b16 * LSEQ * 16 + i];
  for (int i = tid; i < 16 * PAD; i += 512)
    (&s_hb[0][0])[i] = (__bf16)0.0f;

  const float* srcx = h_states + ((size_t)(bb + rA) * LSEQ) * DDIM + g * 8;

  float4 xA[8], xB[8];
#pragma unroll
  for (int kt = 0; kt < 4; ++kt) {  // x(0) -> xB (consumed for step-0 accs now)
    xB[2 * kt] = *(const float4*)(srcx + kt * 32);
    xB[2 * kt + 1] = *(const float4*)(srcx + kt * 32 + 4);
  }
  f32x4 axr0 = {biasr, biasr, biasr, biasr};
  f32x4 axu0 = {biasu, biasu, biasu, biasu};
  f32x4 axh0 = {biash, biash, biash, biash};
#pragma unroll
  for (int kt = 0; kt < 4; ++kt) {
    bf16x8 a = pack8(xB[2 * kt], xB[2 * kt + 1]);
    axr0 = mfma16(a, wr[kt], axr0);
    axu0 = mfma16(a, wu[kt], axu0);
    axh0 = mfma16(a, wh[kt], axh0);
  }
#pragma unroll
  for (int kt = 0; kt < 4; ++kt) {  // x(1) -> xA
    xA[2 * kt] = *(const float4*)(srcx + DDIM + kt * 32);
    xA[2 * kt + 1] = *(const float4*)(srcx + DDIM + kt * 32 + 4);
  }
  f32x4 axr1, axu1, axh1;
  float hD[4] = {0.f, 0.f, 0.f, 0.f};
  __syncthreads();

  for (int t = 0; t < LSEQ; t += 2) {
    STEP(t, xA, xB, axr0, axu0, axh0, axr1, axu1, axh1);
    STEP(t + 1, xB, xA, axr1, axu1, axh1, axr0, axu0, axh0);
  }

#pragma unroll
  for (int j = 0; j < 4; ++j)
    out[(size_t)(bb + g * 4 + j) * DDIM + col] = hD[j];
}

extern "C" void kernel_launch(void* const* d_in, const int* in_sizes, int n_in,
                              void* d_out, int out_size, void* d_ws, size_t ws_size,
                              hipStream_t stream) {
  const float* h_states = (const float*)d_in[0];
  const float* target   = (const float*)d_in[1];
  const int*   mask     = (const int*)d_in[2];
  const float* Wr = (const float*)d_in[3];
  const float* br = (const float*)d_in[4];
  const float* Wu = (const float*)d_in[5];
  const float* bu = (const float*)d_in[6];
  const float* Wh = (const float*)d_in[7];
  const float* bh = (const float*)d_in[8];

  const int B = in_sizes[0] / (LSEQ * DDIM);  // 4096
  float* attnT = (float*)d_ws;                // B*LSEQ floats (b16-major)

  k_scores<<<B / 16, 512, 0, stream>>>(h_states, target, mask, attnT, B);
  k_recur<<<B / 16, 512, 0, stream>>>(h_states, attnT, Wr, br, Wu, bu, Wh, bh,
                                      (float*)d_out, B);
}

// Round 4
// 347.363 us; speedup vs baseline: 2.0051x; 2.0051x over previous
//
#include <hip/hip_runtime.h>
#include <hip/hip_bf16.h>
#include <stdint.h>

#define LSEQ 200
#define DDIM 128

typedef __attribute__((ext_vector_type(8))) __bf16 bf16x8;
typedef __attribute__((ext_vector_type(4))) float f32x4;

__device__ __forceinline__ float fast_exp(float x) {
  return __builtin_amdgcn_exp2f(x * 1.4426950408889634f);
}
__device__ __forceinline__ float fast_sigmoid(float x) {
  return __builtin_amdgcn_rcpf(1.0f + fast_exp(-x));
}
__device__ __forceinline__ float fast_tanh(float x) {
  float ax = __builtin_fabsf(x);
  float t = __builtin_amdgcn_exp2f(ax * -2.885390081777927f);  // exp(-2|x|)
  float r = (1.0f - t) * __builtin_amdgcn_rcpf(1.0f + t);
  return x < 0.0f ? -r : r;
}
__device__ __forceinline__ f32x4 mfma16(bf16x8 a, bf16x8 b, f32x4 c) {
  return __builtin_amdgcn_mfma_f32_16x16x32_bf16(a, b, c, 0, 0, 0);
}

// Kernel 1: scores + masked softmax -> attnT (block-major, 0 where masked),
// and h_states fp32 -> bf16 xp packed in MFMA A-frag order:
// xp[((b16*L + t)*4 + kt)*64 + lane] elem j = x[b16*16+(lane&15)][t][kt*32+(lane>>4)*8+j]
__global__ __launch_bounds__(512) void k_scores(
    const float* __restrict__ h_states, const float* __restrict__ target,
    const int* __restrict__ mask, uint4* __restrict__ xp,
    float* __restrict__ attnT, int B) {
  __shared__ float s_sc[4][16][LSEQ];
  __shared__ float s_tgt[16][DDIM];
  const int b16 = blockIdx.x;
  const int bb = b16 * 16;
  const int tid = threadIdx.x;
  for (int i = tid; i < 16 * DDIM; i += 512)
    s_tgt[i >> 7][i & 127] = target[(size_t)(bb + (i >> 7)) * DDIM + (i & 127)];
  __syncthreads();

  {
    const int lane = tid & 63;
    const int kt = (tid >> 6) & 3;
    const int tp = tid >> 8;
    const int row = lane & 15;
    const int hi = lane >> 4;
    const int kbase = kt * 32 + hi * 8;
    const float* src = h_states + ((size_t)(bb + row) * LSEQ) * DDIM + kbase;
    const float* tg = &s_tgt[row][kbase];
#pragma unroll 2
    for (int t = tp; t < LSEQ; t += 2) {
      float4 a = *(const float4*)(src + (size_t)t * DDIM);
      float4 b = *(const float4*)(src + (size_t)t * DDIM + 4);
      float dv = (a.x * tg[0] + a.y * tg[1] + a.z * tg[2] + a.w * tg[3]) +
                 (b.x * tg[4] + b.y * tg[5] + b.z * tg[6] + b.w * tg[7]);
      dv += __shfl_xor(dv, 16);
      dv += __shfl_xor(dv, 32);
      if (hi == 0) s_sc[kt][row][t] = dv;
      union { __bf16 h[8]; uint4 v; } pk;
      pk.h[0] = (__bf16)a.x; pk.h[1] = (__bf16)a.y; pk.h[2] = (__bf16)a.z; pk.h[3] = (__bf16)a.w;
      pk.h[4] = (__bf16)b.x; pk.h[5] = (__bf16)b.y; pk.h[6] = (__bf16)b.z; pk.h[7] = (__bf16)b.w;
      xp[(((size_t)b16 * LSEQ + t) * 4 + kt) * 64 + lane] = pk.v;
    }
  }
  __syncthreads();

  if (tid < 256) {
    const int r2 = tid >> 4;
    const int j = tid & 15;
    const int* mrow = mask + (size_t)(bb + r2) * LSEQ;
    float mx = -3.0e38f;
    for (int t = j; t < LSEQ; t += 16) {
      float s = (s_sc[0][r2][t] + s_sc[1][r2][t]) + (s_sc[2][r2][t] + s_sc[3][r2][t]);
      s *= 0.088388347648318447f;  // 1/sqrt(128)
      s = (mrow[t] != 0) ? s : -3.0e38f;
      s_sc[0][r2][t] = s;
      mx = fmaxf(mx, s);
    }
    mx = fmaxf(mx, __shfl_xor(mx, 1));
    mx = fmaxf(mx, __shfl_xor(mx, 2));
    mx = fmaxf(mx, __shfl_xor(mx, 4));
    mx = fmaxf(mx, __shfl_xor(mx, 8));
    float se = 0.0f;
    for (int t = j; t < LSEQ; t += 16) {
      float e = fast_exp(s_sc[0][r2][t] - mx);
      s_sc[1][r2][t] = e;
      se += e;
    }
    se += __shfl_xor(se, 1);
    se += __shfl_xor(se, 2);
    se += __shfl_xor(se, 4);
    se += __shfl_xor(se, 8);
    float rs = __builtin_amdgcn_rcpf(se);
    for (int t = j; t < LSEQ; t += 16)
      attnT[((size_t)b16 * LSEQ + t) * 16 + r2] =
          (mrow[t] != 0) ? s_sc[1][r2][t] * rs : 0.0f;
  }
}

// One recurrence step. XC = frags of x_{t+1} (feeds next step's x-part accs);
// XN receives prefetch of x_{t+2}. AX*C = precomputed biased x-part accs for t.
#define STEP(t, XC, XN, AXRC, AXUC, AXHC, AXRN, AXUN, AXHN)                  \
  do {                                                                       \
    if ((t) + 2 < LSEQ) {                                                    \
      _Pragma("unroll") for (int kt = 0; kt < 4; ++kt)                       \
          XN[kt] = xpb[((size_t)(t) + 2) * 256 + kt * 64];                   \
    }                                                                        \
    f32x4 att4 = *(const f32x4*)&s_att[(t)][g * 4];                          \
    bf16x8 hf[4];                                                            \
    _Pragma("unroll") for (int kt = 0; kt < 4; ++kt)                         \
        hf[kt] = __builtin_bit_cast(bf16x8, s_hb_f[kt][lane]);               \
    f32x4 accr = AXRC, accu = AXUC;                                          \
    if ((t) + 1 < LSEQ) { /* next step's x-part: independent MFMAs */        \
      AXRN = (f32x4){biasr, biasr, biasr, biasr};                            \
      AXUN = (f32x4){biasu, biasu, biasu, biasu};                            \
      _Pragma("unroll") for (int kt = 0; kt < 4; ++kt) {                     \
        bf16x8 a = __builtin_bit_cast(bf16x8, XC[kt]);                       \
        AXRN = mfma16(a, wr[kt], AXRN);                                      \
        AXUN = mfma16(a, wu[kt], AXUN);                                      \
      }                                                                      \
    }                                                                        \
    _Pragma("unroll") for (int kt = 0; kt < 4; ++kt) {                       \
      accr = mfma16(hf[kt], wr[4 + kt], accr);                               \
      accu = mfma16(hf[kt], wu[4 + kt], accu);                               \
    }                                                                        \
    float rr[4], uu[4];                                                      \
    _Pragma("unroll") for (int j = 0; j < 4; ++j) {                          \
      rr[j] = fast_sigmoid(accr[j]);                                         \
      uu[j] = fast_sigmoid(accu[j]);                                         \
      rh_w[j * 8] = (__bf16)(rr[j] * hD[j]);                                 \
    }                                                                        \
    __builtin_amdgcn_sched_barrier(0);                                       \
    asm volatile("s_waitcnt lgkmcnt(0)" ::: "memory");                       \
    __builtin_amdgcn_s_barrier();                                            \
    __builtin_amdgcn_sched_barrier(0);                                       \
    bf16x8 rf[4];                                                            \
    _Pragma("unroll") for (int kt = 0; kt < 4; ++kt)                         \
        rf[kt] = __builtin_bit_cast(bf16x8, s_rh_f[kt][lane]);               \
    f32x4 acch = AXHC;                                                       \
    if ((t) + 1 < LSEQ) {                                                    \
      AXHN = (f32x4){biash, biash, biash, biash};                            \
      _Pragma("unroll") for (int kt = 0; kt < 4; ++kt)                       \
          AXHN = mfma16(__builtin_bit_cast(bf16x8, XC[kt]), wh[kt], AXHN);   \
    }                                                                        \
    _Pragma("unroll") for (int kt = 0; kt < 4; ++kt)                         \
        acch = mfma16(rf[kt], wh[4 + kt], acch);                             \
    _Pragma("unroll") for (int j = 0; j < 4; ++j) {                          \
      float ht = fast_tanh(acch[j]);                                         \
      float up = att4[j] * uu[j];                                            \
      hD[j] += up * (ht - hD[j]);                                            \
      hb_w[j * 8] = (__bf16)hD[j];                                           \
    }                                                                        \
    __builtin_amdgcn_sched_barrier(0);                                       \
    asm volatile("s_waitcnt lgkmcnt(0)" ::: "memory");                       \
    __builtin_amdgcn_s_barrier();                                            \
    __builtin_amdgcn_sched_barrier(0);                                       \
  } while (0)

__global__ __launch_bounds__(512, 2) void k_recur(
    const uint4* __restrict__ xp, const float* __restrict__ attnT,
    const float* __restrict__ Wr, const float* __restrict__ br,
    const float* __restrict__ Wu, const float* __restrict__ bu,
    const float* __restrict__ Wh, const float* __restrict__ bh,
    float* __restrict__ out, int B) {
  // h and r*h staged in LDS directly in MFMA A-frag layout:
  // cell [kt][l] elem j  =  value for A-row (l&15), K-col kt*32+(l>>4)*8+j.
  // Reads are ds_read_b128 at lane*16 -> linear, conflict-free, wave-uniform.
  __shared__ uint4 s_hb_f[4][64];
  __shared__ uint4 s_rh_f[4][64];
  __shared__ float s_att[LSEQ][16];
  const int tid = threadIdx.x;
  const int lane = tid & 63;
  const int wv = tid >> 6;
  const int b16 = blockIdx.x;
  const int bb = b16 * 16;
  const int g = lane >> 4;
  const int rA = lane & 15;
  const int col = wv * 16 + rA;

  // Weights -> bf16 B-frags in VGPRs (resident all 200 steps)
  bf16x8 wr[8], wu[8], wh[8];
#pragma unroll
  for (int kt = 0; kt < 8; ++kt) {
    bf16x8 tr, tu, th;
    int krow = kt * 32 + g * 8;
#pragma unroll
    for (int j = 0; j < 8; ++j) {
      tr[j] = (__bf16)Wr[(size_t)(krow + j) * DDIM + col];
      tu[j] = (__bf16)Wu[(size_t)(krow + j) * DDIM + col];
      th[j] = (__bf16)Wh[(size_t)(krow + j) * DDIM + col];
    }
    wr[kt] = tr; wu[kt] = tu; wh[kt] = th;
  }
  const float biasr = br[col], biasu = bu[col], biash = bh[col];

  for (int i = tid; i < LSEQ * 16; i += 512)
    s_att[i >> 4][i & 15] = attnT[(size_t)b16 * LSEQ * 16 + i];
  if (tid < 256) s_hb_f[0][tid & 255] = (uint4){0, 0, 0, 0};  // [4][64] flat

  // Writer pointers into the frag buffers: this thread's 4 h values (rows
  // g*4+j, col) land at frag cell [wv>>1][(g*4+j)+16*hi_w] elem (rA&7).
  const int hi_w = (wv & 1) * 2 + (rA >> 3);
  const int e_w = rA & 7;
  __bf16* hb_w = (__bf16*)s_hb_f + (wv >> 1) * 512 + hi_w * 128 + g * 32 + e_w;
  __bf16* rh_w = (__bf16*)s_rh_f + (wv >> 1) * 512 + hi_w * 128 + g * 32 + e_w;

  const uint4* xpb = xp + (size_t)b16 * LSEQ * 256 + lane;

  uint4 xT[4], xA[4], xB[4];
#pragma unroll
  for (int kt = 0; kt < 4; ++kt) xT[kt] = xpb[kt * 64];          // x(0)
#pragma unroll
  for (int kt = 0; kt < 4; ++kt) xA[kt] = xpb[256 + kt * 64];    // x(1)
  f32x4 axr0 = {biasr, biasr, biasr, biasr};
  f32x4 axu0 = {biasu, biasu, biasu, biasu};
  f32x4 axh0 = {biash, biash, biash, biash};
#pragma unroll
  for (int kt = 0; kt < 4; ++kt) {
    bf16x8 a = __builtin_bit_cast(bf16x8, xT[kt]);
    axr0 = mfma16(a, wr[kt], axr0);
    axu0 = mfma16(a, wu[kt], axu0);
    axh0 = mfma16(a, wh[kt], axh0);
  }
  f32x4 axr1, axu1, axh1;
  float hD[4] = {0.f, 0.f, 0.f, 0.f};
  __syncthreads();

  for (int t = 0; t < LSEQ; t += 2) {
    STEP(t, xA, xB, axr0, axu0, axh0, axr1, axu1, axh1);
    STEP(t + 1, xB, xA, axr1, axu1, axh1, axr0, axu0, axh0);
  }

#pragma unroll
  for (int j = 0; j < 4; ++j)
    out[(size_t)(bb + g * 4 + j) * DDIM + col] = hD[j];
}

extern "C" void kernel_launch(void* const* d_in, const int* in_sizes, int n_in,
                              void* d_out, int out_size, void* d_ws, size_t ws_size,
                              hipStream_t stream) {
  const float* h_states = (const float*)d_in[0];
  const float* target   = (const float*)d_in[1];
  const int*   mask     = (const int*)d_in[2];
  const float* Wr = (const float*)d_in[3];
  const float* br = (const float*)d_in[4];
  const float* Wu = (const float*)d_in[5];
  const float* bu = (const float*)d_in[6];
  const float* Wh = (const float*)d_in[7];
  const float* bh = (const float*)d_in[8];

  const int B = in_sizes[0] / (LSEQ * DDIM);  // 4096
  uint4* xp = (uint4*)d_ws;                    // B*L*128 bf16 A-frags
  float* attnT = (float*)((char*)d_ws + (size_t)B * LSEQ * DDIM * 2);

  k_scores<<<B / 16, 512, 0, stream>>>(h_states, target, mask, xp, attnT, B);
  k_recur<<<B / 16, 512, 0, stream>>>(xp, attnT, Wr, br, Wu, bu, Wh, bh,
                                      (float*)d_out, B);
}

// Round 6
// 341.480 us; speedup vs baseline: 2.0396x; 1.0172x over previous
//
#include <hip/hip_runtime.h>
#include <hip/hip_bf16.h>
#include <stdint.h>

#define LSEQ 200
#define DDIM 128

typedef __attribute__((ext_vector_type(8))) __bf16 bf16x8;
typedef __attribute__((ext_vector_type(4))) float f32x4;

__device__ __forceinline__ float fast_exp(float x) {
  return __builtin_amdgcn_exp2f(x * 1.4426950408889634f);
}
__device__ __forceinline__ float fast_sigmoid(float x) {
  return __builtin_amdgcn_rcpf(1.0f + fast_exp(-x));
}
__device__ __forceinline__ float fast_tanh(float x) {
  float ax = __builtin_fabsf(x);
  float t = __builtin_amdgcn_exp2f(ax * -2.885390081777927f);  // exp(-2|x|)
  float r = (1.0f - t) * __builtin_amdgcn_rcpf(1.0f + t);
  return x < 0.0f ? -r : r;
}
__device__ __forceinline__ f32x4 mfma16(bf16x8 a, bf16x8 b, f32x4 c) {
  return __builtin_amdgcn_mfma_f32_16x16x32_bf16(a, b, c, 0, 0, 0);
}

// Kernel 1: scores + masked softmax -> attnT (block-major, 0 where masked),
// and h_states fp32 -> bf16 xp packed in frag order:
// xp[((b16*L + t)*4 + kt)*64 + lane] elem j = x[b16*16+(lane&15)][t][kt*32+(lane>>4)*8+j]
// (valid as both A-frag [batch][d] and B-frag [d][batch] under MFMA lane rules)
__global__ __launch_bounds__(512) void k_scores(
    const float* __restrict__ h_states, const float* __restrict__ target,
    const int* __restrict__ mask, uint4* __restrict__ xp,
    float* __restrict__ attnT, int B) {
  __shared__ float s_sc[4][16][LSEQ];
  __shared__ float s_tgt[16][DDIM];
  const int b16 = blockIdx.x;
  const int bb = b16 * 16;
  const int tid = threadIdx.x;
  for (int i = tid; i < 16 * DDIM; i += 512)
    s_tgt[i >> 7][i & 127] = target[(size_t)(bb + (i >> 7)) * DDIM + (i & 127)];
  __syncthreads();

  {
    const int lane = tid & 63;
    const int kt = (tid >> 6) & 3;
    const int tp = tid >> 8;
    const int row = lane & 15;
    const int hi = lane >> 4;
    const int kbase = kt * 32 + hi * 8;
    const float* src = h_states + ((size_t)(bb + row) * LSEQ) * DDIM + kbase;
    const float* tg = &s_tgt[row][kbase];
#pragma unroll 2
    for (int t = tp; t < LSEQ; t += 2) {
      float4 a = *(const float4*)(src + (size_t)t * DDIM);
      float4 b = *(const float4*)(src + (size_t)t * DDIM + 4);
      float dv = (a.x * tg[0] + a.y * tg[1] + a.z * tg[2] + a.w * tg[3]) +
                 (b.x * tg[4] + b.y * tg[5] + b.z * tg[6] + b.w * tg[7]);
      dv += __shfl_xor(dv, 16);
      dv += __shfl_xor(dv, 32);
      if (hi == 0) s_sc[kt][row][t] = dv;
      union { __bf16 h[8]; uint4 v; } pk;
      pk.h[0] = (__bf16)a.x; pk.h[1] = (__bf16)a.y; pk.h[2] = (__bf16)a.z; pk.h[3] = (__bf16)a.w;
      pk.h[4] = (__bf16)b.x; pk.h[5] = (__bf16)b.y; pk.h[6] = (__bf16)b.z; pk.h[7] = (__bf16)b.w;
      xp[(((size_t)b16 * LSEQ + t) * 4 + kt) * 64 + lane] = pk.v;
    }
  }
  __syncthreads();

  if (tid < 256) {
    const int r2 = tid >> 4;
    const int j = tid & 15;
    const int* mrow = mask + (size_t)(bb + r2) * LSEQ;
    float mx = -3.0e38f;
    for (int t = j; t < LSEQ; t += 16) {
      float s = (s_sc[0][r2][t] + s_sc[1][r2][t]) + (s_sc[2][r2][t] + s_sc[3][r2][t]);
      s *= 0.088388347648318447f;  // 1/sqrt(128)
      s = (mrow[t] != 0) ? s : -3.0e38f;
      s_sc[0][r2][t] = s;
      mx = fmaxf(mx, s);
    }
    mx = fmaxf(mx, __shfl_xor(mx, 1));
    mx = fmaxf(mx, __shfl_xor(mx, 2));
    mx = fmaxf(mx, __shfl_xor(mx, 4));
    mx = fmaxf(mx, __shfl_xor(mx, 8));
    float se = 0.0f;
    for (int t = j; t < LSEQ; t += 16) {
      float e = fast_exp(s_sc[0][r2][t] - mx);
      s_sc[1][r2][t] = e;
      se += e;
    }
    se += __shfl_xor(se, 1);
    se += __shfl_xor(se, 2);
    se += __shfl_xor(se, 4);
    se += __shfl_xor(se, 8);
    float rs = __builtin_amdgcn_rcpf(se);
    for (int t = j; t < LSEQ; t += 16)
      attnT[((size_t)b16 * LSEQ + t) * 16 + r2] =
          (mrow[t] != 0) ? s_sc[1][r2][t] * rs : 0.0f;
  }
}

// One step, operand-swapped: D[col][batch] = W^T-frags (A) x h^T-frags (B).
// Thread (wv,lane) owns batch row rA=lane&15, cols wv*16 + q*4 .. +3 (q=lane>>4).
// LDS exchange write = ONE ds_write_b64/thread; reads = linear ds_read_b128.
#define STEP(t, XC, XN, AXRC, AXUC, AXHC, AXRN, AXUN, AXHN)                  \
  do {                                                                       \
    if ((t) + 2 < LSEQ) {                                                    \
      _Pragma("unroll") for (int kt = 0; kt < 4; ++kt)                       \
          XN[kt] = xpb[((size_t)(t) + 2) * 256 + kt * 64];                   \
    }                                                                        \
    float att = s_att[(t)][rA];                                              \
    bf16x8 hf[4];                                                            \
    _Pragma("unroll") for (int kt = 0; kt < 4; ++kt)                         \
        hf[kt] = __builtin_bit_cast(bf16x8, s_hb_f[kt][lane]);               \
    if ((t) + 1 < LSEQ) { /* next step's x-part: independent MFMAs */        \
      AXRN = vbr;                                                            \
      AXUN = vbu;                                                            \
      _Pragma("unroll") for (int kt = 0; kt < 4; ++kt) {                     \
        bf16x8 b = __builtin_bit_cast(bf16x8, XC[kt]);                       \
        AXRN = mfma16(wr[kt], b, AXRN);                                      \
        AXUN = mfma16(wu[kt], b, AXUN);                                      \
      }                                                                      \
    }                                                                        \
    f32x4 r1 = AXRC, u1 = AXUC;                                              \
    f32x4 r2 = {0.f, 0.f, 0.f, 0.f}, u2 = {0.f, 0.f, 0.f, 0.f};              \
    r1 = mfma16(wr[4], hf[0], r1); u1 = mfma16(wu[4], hf[0], u1);            \
    r2 = mfma16(wr[6], hf[2], r2); u2 = mfma16(wu[6], hf[2], u2);            \
    r1 = mfma16(wr[5], hf[1], r1); u1 = mfma16(wu[5], hf[1], u1);            \
    r2 = mfma16(wr[7], hf[3], r2); u2 = mfma16(wu[7], hf[3], u2);            \
    f32x4 accr = r1 + r2, accu = u1 + u2;                                    \
    float rr[4], uu[4];                                                      \
    union { __bf16 h[4]; uint2 v; } rhv;                                     \
    _Pragma("unroll") for (int j = 0; j < 4; ++j) {                          \
      rr[j] = fast_sigmoid(accr[j]);                                         \
      uu[j] = fast_sigmoid(accu[j]);                                         \
      rhv.h[j] = (__bf16)(rr[j] * hD[j]);                                    \
    }                                                                        \
    *rh_w = rhv.v;                                                           \
    asm volatile("s_waitcnt lgkmcnt(0)" ::: "memory");                       \
    __builtin_amdgcn_s_barrier();                                            \
    __builtin_amdgcn_sched_barrier(0);                                       \
    bf16x8 rf[4];                                                            \
    _Pragma("unroll") for (int kt = 0; kt < 4; ++kt)                         \
        rf[kt] = __builtin_bit_cast(bf16x8, s_rh_f[kt][lane]);               \
    if ((t) + 1 < LSEQ) {                                                    \
      AXHN = vbh;                                                            \
      _Pragma("unroll") for (int kt = 0; kt < 4; ++kt)                       \
          AXHN = mfma16(wh[kt], __builtin_bit_cast(bf16x8, XC[kt]), AXHN);   \
    }                                                                        \
    f32x4 h1 = AXHC, h2 = {0.f, 0.f, 0.f, 0.f};                              \
    h1 = mfma16(wh[4], rf[0], h1);                                           \
    h2 = mfma16(wh[6], rf[2], h2);                                           \
    h1 = mfma16(wh[5], rf[1], h1);                                           \
    h2 = mfma16(wh[7], rf[3], h2);                                           \
    f32x4 acch = h1 + h2;                                                    \
    union { __bf16 h[4]; uint2 v; } hbv;                                     \
    _Pragma("unroll") for (int j = 0; j < 4; ++j) {                          \
      float ht = fast_tanh(acch[j]);                                         \
      float up = att * uu[j];                                                \
      hD[j] += up * (ht - hD[j]);                                            \
      hbv.h[j] = (__bf16)hD[j];                                              \
    }                                                                        \
    *hb_w = hbv.v;                                                           \
    asm volatile("s_waitcnt lgkmcnt(0)" ::: "memory");                       \
    __builtin_amdgcn_s_barrier();                                            \
    __builtin_amdgcn_sched_barrier(0);                                       \
  } while (0)

__global__ __launch_bounds__(512, 2) void k_recur(
    const uint4* __restrict__ xp, const float* __restrict__ attnT,
    const float* __restrict__ Wr, const float* __restrict__ br,
    const float* __restrict__ Wu, const float* __restrict__ bu,
    const float* __restrict__ Wh, const float* __restrict__ bh,
    float* __restrict__ out, int B) {
  // h and r*h staged in LDS in B-frag layout:
  // cell [kt][l] elem j = value[batch=l&15][d = kt*32 + (l>>4)*8 + j].
  __shared__ uint4 s_hb_f[4][64];
  __shared__ uint4 s_rh_f[4][64];
  __shared__ float s_att[LSEQ][16];
  const int tid = threadIdx.x;
  const int lane = tid & 63;
  const int wv = tid >> 6;
  const int b16 = blockIdx.x;
  const int bb = b16 * 16;
  const int q = lane >> 4;
  const int rA = lane & 15;
  const int col = wv * 16 + rA;   // column index used for WEIGHT loading only

  // Weights -> bf16 frags in VGPRs (A-operand under swap; same layout as before)
  bf16x8 wr[8], wu[8], wh[8];
#pragma unroll
  for (int kt = 0; kt < 8; ++kt) {
    bf16x8 tr, tu, th;
    int krow = kt * 32 + q * 8;
#pragma unroll
    for (int j = 0; j < 8; ++j) {
      tr[j] = (__bf16)Wr[(size_t)(krow + j) * DDIM + col];
      tu[j] = (__bf16)Wu[(size_t)(krow + j) * DDIM + col];
      th[j] = (__bf16)Wh[(size_t)(krow + j) * DDIM + col];
    }
    wr[kt] = tr; wu[kt] = tu; wh[kt] = th;
  }
  // Biases for this thread's 4 output cols (wv*16 + q*4 + j)
  const int cbase = wv * 16 + q * 4;
  f32x4 vbr = {br[cbase], br[cbase + 1], br[cbase + 2], br[cbase + 3]};
  f32x4 vbu = {bu[cbase], bu[cbase + 1], bu[cbase + 2], bu[cbase + 3]};
  f32x4 vbh = {bh[cbase], bh[cbase + 1], bh[cbase + 2], bh[cbase + 3]};

  for (int i = tid; i < LSEQ * 16; i += 512)
    s_att[i >> 4][i & 15] = attnT[(size_t)b16 * LSEQ * 16 + i];
  if (tid < 256) s_hb_f[0][tid & 255] = (uint4){0, 0, 0, 0};  // zero [4][64]

  // Writer: thread's 4 values (batch rA, cols cbase..cbase+3) -> one b64 at
  // frag [wv>>1][rA + 16*((wv&1)*2 + (q>>1))], elems (q&1)*4..+3.
  const int lane_w = rA + 16 * ((wv & 1) * 2 + (q >> 1));
  uint2* hb_w = (uint2*)((char*)s_hb_f + (wv >> 1) * 1024 + lane_w * 16 + (q & 1) * 8);
  uint2* rh_w = (uint2*)((char*)s_rh_f + (wv >> 1) * 1024 + lane_w * 16 + (q & 1) * 8);

  const uint4* xpb = xp + (size_t)b16 * LSEQ * 256 + lane;

  uint4 xT[4], xA[4], xB[4];
#pragma unroll
  for (int kt = 0; kt < 4; ++kt) xT[kt] = xpb[kt * 64];        // x(0)
#pragma unroll
  for (int kt = 0; kt < 4; ++kt) xA[kt] = xpb[256 + kt * 64];  // x(1)
  f32x4 axr0 = vbr, axu0 = vbu, axh0 = vbh;
#pragma unroll
  for (int kt = 0; kt < 4; ++kt) {
    bf16x8 b = __builtin_bit_cast(bf16x8, xT[kt]);
    axr0 = mfma16(wr[kt], b, axr0);
    axu0 = mfma16(wu[kt], b, axu0);
    axh0 = mfma16(wh[kt], b, axh0);
  }
  f32x4 axr1, axu1, axh1;
  float hD[4] = {0.f, 0.f, 0.f, 0.f};
  __syncthreads();

  for (int t = 0; t < LSEQ; t += 2) {
    STEP(t, xA, xB, axr0, axu0, axh0, axr1, axu1, axh1);
    STEP(t + 1, xB, xA, axr1, axu1, axh1, axr0, axu0, axh0);
  }

  float4 o = {hD[0], hD[1], hD[2], hD[3]};
  *(float4*)(out + (size_t)(bb + rA) * DDIM + cbase) = o;
}

extern "C" void kernel_launch(void* const* d_in, const int* in_sizes, int n_in,
                              void* d_out, int out_size, void* d_ws, size_t ws_size,
                              hipStream_t stream) {
  const float* h_states = (const float*)d_in[0];
  const float* target   = (const float*)d_in[1];
  const int*   mask     = (const int*)d_in[2];
  const float* Wr = (const float*)d_in[3];
  const float* br = (const float*)d_in[4];
  const float* Wu = (const float*)d_in[5];
  const float* bu = (const float*)d_in[6];
  const float* Wh = (const float*)d_in[7];
  const float* bh = (const float*)d_in[8];

  const int B = in_sizes[0] / (LSEQ * DDIM);  // 4096
  uint4* xp = (uint4*)d_ws;                    // B*L*128 bf16 frags
  float* attnT = (float*)((char*)d_ws + (size_t)B * LSEQ * DDIM * 2);

  k_scores<<<B / 16, 512, 0, stream>>>(h_states, target, mask, xp, attnT, B);
  k_recur<<<B / 16, 512, 0, stream>>>(xp, attnT, Wr, br, Wu, bu, Wh, bh,
                                      (float*)d_out, B);
}

// Round 7
// 318.249 us; speedup vs baseline: 2.1885x; 1.0730x over previous
//
#include <hip/hip_runtime.h>
#include <hip/hip_bf16.h>
#include <stdint.h>

#define LSEQ 200
#define DDIM 128

typedef __attribute__((ext_vector_type(8))) __bf16 bf16x8;
typedef __attribute__((ext_vector_type(4))) float f32x4;

__device__ __forceinline__ float fast_exp(float x) {
  return __builtin_amdgcn_exp2f(x * 1.4426950408889634f);
}
__device__ __forceinline__ float fast_sigmoid(float x) {
  return __builtin_amdgcn_rcpf(1.0f + fast_exp(-x));
}
__device__ __forceinline__ float fast_tanh(float x) {
  float ax = __builtin_fabsf(x);
  float t = __builtin_amdgcn_exp2f(ax * -2.885390081777927f);  // exp(-2|x|)
  float r = (1.0f - t) * __builtin_amdgcn_rcpf(1.0f + t);
  return x < 0.0f ? -r : r;
}
__device__ __forceinline__ f32x4 mfma16(bf16x8 a, bf16x8 b, f32x4 c) {
  return __builtin_amdgcn_mfma_f32_16x16x32_bf16(a, b, c, 0, 0, 0);
}

// Kernel 1: scores + masked softmax -> attnT (block-major, 0 where masked),
// and h_states fp32 -> bf16 xp packed in frag order:
// xp[((b16*L + t)*4 + kt)*64 + lane] elem j = x[b16*16+(lane&15)][t][kt*32+(lane>>4)*8+j]
__global__ __launch_bounds__(512) void k_scores(
    const float* __restrict__ h_states, const float* __restrict__ target,
    const int* __restrict__ mask, uint4* __restrict__ xp,
    float* __restrict__ attnT, int B) {
  __shared__ float s_sc[4][16][LSEQ];
  __shared__ float s_tgt[16][DDIM];
  const int b16 = blockIdx.x;
  const int bb = b16 * 16;
  const int tid = threadIdx.x;
  for (int i = tid; i < 16 * DDIM; i += 512)
    s_tgt[i >> 7][i & 127] = target[(size_t)(bb + (i >> 7)) * DDIM + (i & 127)];
  __syncthreads();

  {
    const int lane = tid & 63;
    const int kt = (tid >> 6) & 3;
    const int tp = tid >> 8;
    const int row = lane & 15;
    const int hi = lane >> 4;
    const int kbase = kt * 32 + hi * 8;
    const float* src = h_states + ((size_t)(bb + row) * LSEQ) * DDIM + kbase;
    const float* tg = &s_tgt[row][kbase];
#pragma unroll 2
    for (int t = tp; t < LSEQ; t += 2) {
      float4 a = *(const float4*)(src + (size_t)t * DDIM);
      float4 b = *(const float4*)(src + (size_t)t * DDIM + 4);
      float dv = (a.x * tg[0] + a.y * tg[1] + a.z * tg[2] + a.w * tg[3]) +
                 (b.x * tg[4] + b.y * tg[5] + b.z * tg[6] + b.w * tg[7]);
      dv += __shfl_xor(dv, 16);
      dv += __shfl_xor(dv, 32);
      if (hi == 0) s_sc[kt][row][t] = dv;
      union { __bf16 h[8]; uint4 v; } pk;
      pk.h[0] = (__bf16)a.x; pk.h[1] = (__bf16)a.y; pk.h[2] = (__bf16)a.z; pk.h[3] = (__bf16)a.w;
      pk.h[4] = (__bf16)b.x; pk.h[5] = (__bf16)b.y; pk.h[6] = (__bf16)b.z; pk.h[7] = (__bf16)b.w;
      xp[(((size_t)b16 * LSEQ + t) * 4 + kt) * 64 + lane] = pk.v;
    }
  }
  __syncthreads();

  if (tid < 256) {
    const int r2 = tid >> 4;
    const int j = tid & 15;
    const int* mrow = mask + (size_t)(bb + r2) * LSEQ;
    float mx = -3.0e38f;
    for (int t = j; t < LSEQ; t += 16) {
      float s = (s_sc[0][r2][t] + s_sc[1][r2][t]) + (s_sc[2][r2][t] + s_sc[3][r2][t]);
      s *= 0.088388347648318447f;  // 1/sqrt(128)
      s = (mrow[t] != 0) ? s : -3.0e38f;
      s_sc[0][r2][t] = s;
      mx = fmaxf(mx, s);
    }
    mx = fmaxf(mx, __shfl_xor(mx, 1));
    mx = fmaxf(mx, __shfl_xor(mx, 2));
    mx = fmaxf(mx, __shfl_xor(mx, 4));
    mx = fmaxf(mx, __shfl_xor(mx, 8));
    float se = 0.0f;
    for (int t = j; t < LSEQ; t += 16) {
      float e = fast_exp(s_sc[0][r2][t] - mx);
      s_sc[1][r2][t] = e;
      se += e;
    }
    se += __shfl_xor(se, 1);
    se += __shfl_xor(se, 2);
    se += __shfl_xor(se, 4);
    se += __shfl_xor(se, 8);
    float rs = __builtin_amdgcn_rcpf(se);
    for (int t = j; t < LSEQ; t += 16)
      attnT[((size_t)b16 * LSEQ + t) * 16 + r2] =
          (mrow[t] != 0) ? s_sc[1][r2][t] * rs : 0.0f;
  }
}

#define LGKM_BARRIER()                                 \
  asm volatile("s_waitcnt lgkmcnt(0)" ::: "memory");   \
  __builtin_amdgcn_s_barrier();                        \
  asm volatile("" ::: "memory")

// One step, operand-swapped (A = weight frags, B = h/x frags).
// XC = frags of x(t+1); XN = buffer receiving prefetch of x(t+4).
// Independent x-part MFMAs + prefetch fill the LDS read/write latency windows.
#define STEP(t, XC, XN, AXRC, AXUC, AXHC, AXRN, AXUN, AXHN)                  \
  do {                                                                       \
    /* ---- phase A ---- */                                                  \
    const int tl = ((t) + 4 < LSEQ) ? (t) + 4 : LSEQ - 4;                    \
    _Pragma("unroll") for (int kt = 0; kt < 4; ++kt)                         \
        XN[kt] = xpb[(size_t)tl * 256 + kt * 64];                            \
    float att = s_att[(t)][rA];                                              \
    bf16x8 hf[4];                                                            \
    _Pragma("unroll") for (int kt = 0; kt < 4; ++kt)                         \
        hf[kt] = __builtin_bit_cast(bf16x8, s_hb_f[kt][lane]);               \
    /* window filler: first half of next-step x-part r,u */                  \
    AXRN = vbr; AXUN = vbu;                                                  \
    _Pragma("unroll") for (int kt = 0; kt < 2; ++kt) {                       \
      bf16x8 b = __builtin_bit_cast(bf16x8, XC[kt]);                         \
      AXRN = mfma16(wr[kt], b, AXRN);                                        \
      AXUN = mfma16(wu[kt], b, AXUN);                                        \
    }                                                                        \
    /* dependent: h-part r,u (2+2 split chains) */                           \
    f32x4 r1 = AXRC, u1 = AXUC;                                              \
    f32x4 r2 = {0.f, 0.f, 0.f, 0.f}, u2 = {0.f, 0.f, 0.f, 0.f};              \
    r1 = mfma16(wr[4], hf[0], r1); u1 = mfma16(wu[4], hf[0], u1);            \
    r2 = mfma16(wr[6], hf[2], r2); u2 = mfma16(wu[6], hf[2], u2);            \
    r1 = mfma16(wr[5], hf[1], r1); u1 = mfma16(wu[5], hf[1], u1);            \
    r2 = mfma16(wr[7], hf[3], r2); u2 = mfma16(wu[7], hf[3], u2);            \
    f32x4 accr = r1 + r2, accu = u1 + u2;                                    \
    union { __bf16 h[4]; uint2 v; } rhv;                                     \
    _Pragma("unroll") for (int j = 0; j < 4; ++j)                            \
      rhv.h[j] = (__bf16)(fast_sigmoid(accr[j]) * hD[j]);                    \
    *rh_w = rhv.v;                                                           \
    /* drain-window filler: second half of next-step x-part r,u */           \
    _Pragma("unroll") for (int kt = 2; kt < 4; ++kt) {                       \
      bf16x8 b = __builtin_bit_cast(bf16x8, XC[kt]);                         \
      AXRN = mfma16(wr[kt], b, AXRN);                                        \
      AXUN = mfma16(wu[kt], b, AXUN);                                        \
    }                                                                        \
    LGKM_BARRIER();                                                          \
    /* ---- phase B ---- */                                                  \
    bf16x8 rf[4];                                                            \
    _Pragma("unroll") for (int kt = 0; kt < 4; ++kt)                         \
        rf[kt] = __builtin_bit_cast(bf16x8, s_rh_f[kt][lane]);               \
    /* window fillers: u-sigmoids + next-step x-part h */                    \
    float uu[4];                                                             \
    _Pragma("unroll") for (int j = 0; j < 4; ++j)                            \
      uu[j] = fast_sigmoid(accu[j]);                                         \
    AXHN = vbh;                                                              \
    _Pragma("unroll") for (int kt = 0; kt < 4; ++kt)                         \
        AXHN = mfma16(wh[kt], __builtin_bit_cast(bf16x8, XC[kt]), AXHN);     \
    /* dependent: h-part h_tilde */                                          \
    f32x4 h1 = AXHC, h2 = {0.f, 0.f, 0.f, 0.f};                              \
    h1 = mfma16(wh[4], rf[0], h1);                                           \
    h2 = mfma16(wh[6], rf[2], h2);                                           \
    h1 = mfma16(wh[5], rf[1], h1);                                           \
    h2 = mfma16(wh[7], rf[3], h2);                                           \
    f32x4 acch = h1 + h2;                                                    \
    union { __bf16 h[4]; uint2 v; } hbv;                                     \
    _Pragma("unroll") for (int j = 0; j < 4; ++j) {                          \
      float ht = fast_tanh(acch[j]);                                         \
      float up = att * uu[j];                                                \
      hD[j] += up * (ht - hD[j]);                                            \
      hbv.h[j] = (__bf16)hD[j];                                              \
    }                                                                        \
    *hb_w = hbv.v;                                                           \
    LGKM_BARRIER();                                                          \
  } while (0)

__global__ __launch_bounds__(512, 2) void k_recur(
    const uint4* __restrict__ xp, const float* __restrict__ attnT,
    const float* __restrict__ Wr, const float* __restrict__ br,
    const float* __restrict__ Wu, const float* __restrict__ bu,
    const float* __restrict__ Wh, const float* __restrict__ bh,
    float* __restrict__ out, int B) {
  // h and r*h staged in LDS in B-frag layout:
  // cell [kt][l] elem j = value[batch=l&15][d = kt*32 + (l>>4)*8 + j].
  __shared__ uint4 s_hb_f[4][64];
  __shared__ uint4 s_rh_f[4][64];
  __shared__ float s_att[LSEQ][16];
  const int tid = threadIdx.x;
  const int lane = tid & 63;
  const int wv = tid >> 6;
  const int b16 = blockIdx.x;
  const int bb = b16 * 16;
  const int q = lane >> 4;
  const int rA = lane & 15;
  const int col = wv * 16 + rA;  // weight-loading column

  // Weights -> bf16 frags in VGPRs (A-operand; resident all 200 steps)
  bf16x8 wr[8], wu[8], wh[8];
#pragma unroll
  for (int kt = 0; kt < 8; ++kt) {
    bf16x8 tr, tu, th;
    int krow = kt * 32 + q * 8;
#pragma unroll
    for (int j = 0; j < 8; ++j) {
      tr[j] = (__bf16)Wr[(size_t)(krow + j) * DDIM + col];
      tu[j] = (__bf16)Wu[(size_t)(krow + j) * DDIM + col];
      th[j] = (__bf16)Wh[(size_t)(krow + j) * DDIM + col];
    }
    wr[kt] = tr; wu[kt] = tu; wh[kt] = th;
  }
  const int cbase = wv * 16 + q * 4;
  f32x4 vbr = {br[cbase], br[cbase + 1], br[cbase + 2], br[cbase + 3]};
  f32x4 vbu = {bu[cbase], bu[cbase + 1], bu[cbase + 2], bu[cbase + 3]};
  f32x4 vbh = {bh[cbase], bh[cbase + 1], bh[cbase + 2], bh[cbase + 3]};

  for (int i = tid; i < LSEQ * 16; i += 512)
    s_att[i >> 4][i & 15] = attnT[(size_t)b16 * LSEQ * 16 + i];
  if (tid < 256) s_hb_f[0][tid & 255] = (uint4){0, 0, 0, 0};  // zero [4][64]

  // Writer: thread's 4 values (batch rA, cols cbase..+3) -> one b64 at
  // frag [wv>>1][rA + 16*((wv&1)*2 + (q>>1))], elems (q&1)*4..+3.
  const int lane_w = rA + 16 * ((wv & 1) * 2 + (q >> 1));
  uint2* hb_w = (uint2*)((char*)s_hb_f + (wv >> 1) * 1024 + lane_w * 16 + (q & 1) * 8);
  uint2* rh_w = (uint2*)((char*)s_rh_f + (wv >> 1) * 1024 + lane_w * 16 + (q & 1) * 8);

  const uint4* xpb = xp + (size_t)b16 * LSEQ * 256 + lane;

  // Prologue: x(0) -> xb0 (consumed now), x(1..3) -> xb1..xb3 (4-deep pipe)
  uint4 xb0[4], xb1[4], xb2[4], xb3[4];
#pragma unroll
  for (int kt = 0; kt < 4; ++kt) xb0[kt] = xpb[kt * 64];
#pragma unroll
  for (int kt = 0; kt < 4; ++kt) xb1[kt] = xpb[256 + kt * 64];
#pragma unroll
  for (int kt = 0; kt < 4; ++kt) xb2[kt] = xpb[512 + kt * 64];
#pragma unroll
  for (int kt = 0; kt < 4; ++kt) xb3[kt] = xpb[768 + kt * 64];

  f32x4 axr0 = vbr, axu0 = vbu, axh0 = vbh;
#pragma unroll
  for (int kt = 0; kt < 4; ++kt) {
    bf16x8 b = __builtin_bit_cast(bf16x8, xb0[kt]);
    axr0 = mfma16(wr[kt], b, axr0);
    axu0 = mfma16(wu[kt], b, axu0);
    axh0 = mfma16(wh[kt], b, axh0);
  }
  f32x4 axr1, axu1, axh1;
  float hD[4] = {0.f, 0.f, 0.f, 0.f};
  __syncthreads();

  // 4x unrolled: step t consumes XC=xb[(t+1)&3], loads x(t+4) into xb[t&3].
  for (int t = 0; t < LSEQ; t += 4) {
    STEP(t + 0, xb1, xb0, axr0, axu0, axh0, axr1, axu1, axh1);
    STEP(t + 1, xb2, xb1, axr1, axu1, axh1, axr0, axu0, axh0);
    STEP(t + 2, xb3, xb2, axr0, axu0, axh0, axr1, axu1, axh1);
    STEP(t + 3, xb0, xb3, axr1, axu1, axh1, axr0, axu0, axh0);
  }

  float4 o = {hD[0], hD[1], hD[2], hD[3]};
  *(float4*)(out + (size_t)(bb + rA) * DDIM + cbase) = o;
}

extern "C" void kernel_launch(void* const* d_in, const int* in_sizes, int n_in,
                              void* d_out, int out_size, void* d_ws, size_t ws_size,
                              hipStream_t stream) {
  const float* h_states = (const float*)d_in[0];
  const float* target   = (const float*)d_in[1];
  const int*   mask     = (const int*)d_in[2];
  const float* Wr = (const float*)d_in[3];
  const float* br = (const float*)d_in[4];
  const float* Wu = (const float*)d_in[5];
  const float* bu = (const float*)d_in[6];
  const float* Wh = (const float*)d_in[7];
  const float* bh = (const float*)d_in[8];

  const int B = in_sizes[0] / (LSEQ * DDIM);  // 4096
  uint4* xp = (uint4*)d_ws;                    // B*L*128 bf16 frags
  float* attnT = (float*)((char*)d_ws + (size_t)B * LSEQ * DDIM * 2);

  k_scores<<<B / 16, 512, 0, stream>>>(h_states, target, mask, xp, attnT, B);
  k_recur<<<B / 16, 512, 0, stream>>>(xp, attnT, Wr, br, Wu, bu, Wh, bh,
                                      (float*)d_out, B);
}